// Round 8
// baseline (62.815 us; speedup 1.0000x reference)
//
#include <hip/hip_runtime.h>
#include <hip/hip_fp16.h>

typedef _Float16 half8 __attribute__((ext_vector_type(8)));
typedef float floatx4 __attribute__((ext_vector_type(4)));

#define KH 256              // H (inner / K dim)
#define NN 1024             // N heads
#define BM 32               // b-rows per block (all 4 waves share rows, split cols)
#define THREADS 256
#define NGRP 16             // 16-col groups per wave
#define GRP_F16 4096        // one group: 16 n x 256 k f16 = 8 KB

// ---------------- pack kernel: W fp32 -> f16, MFMA-fragment order ----------
// packed f16 index: ((g*8 + ks)*64 + lane)*8 + j
//   where n = g*16 + (lane&15), k = ks*32 + (lane>>4)*8 + j
__global__ __launch_bounds__(256)
void pack_w(const float* __restrict__ W, _Float16* __restrict__ P) {
    const int u  = blockIdx.x * 256 + threadIdx.x;   // 32768 threads total
    const int g  = u >> 9;
    const int ks = (u >> 6) & 7;
    const int l  = u & 63;
    const int n  = g * 16 + (l & 15);
    const int kb = ks * 32 + ((l >> 4) << 3);
    const float* src = W + (size_t)n * KH + kb;
    floatx4 lo = *(const floatx4*)src;
    floatx4 hi = *(const floatx4*)(src + 4);
    half8 h;
    h[0] = (_Float16)lo[0]; h[1] = (_Float16)lo[1];
    h[2] = (_Float16)lo[2]; h[3] = (_Float16)lo[3];
    h[4] = (_Float16)hi[0]; h[5] = (_Float16)hi[1];
    h[6] = (_Float16)hi[2]; h[7] = (_Float16)hi[3];
    *(half8*)(P + (size_t)u * 8) = h;                // fully coalesced 16B/lane
}

// ---- main: 4 fully independent per-wave pipelines, ZERO barriers ----------
__global__ __launch_bounds__(THREADS, 2)
void lfh_main(const float* __restrict__ x, const _Float16* __restrict__ P,
              const float* __restrict__ bias, float* __restrict__ out) {
    __shared__ _Float16 stg[4][2][GRP_F16];   // per-wave private 2x8KB dbuf (64 KB)
    __shared__ float    bls[NN];              // per-wave private 256-f32 windows (4 KB)

    const int t   = threadIdx.x;
    const int w   = t >> 6;       // wave id -> column window [256w, 256w+256)
    const int l   = t & 63;
    const int l15 = l & 15;
    const int lq  = l >> 4;

    const int brow0 = blockIdx.x * BM;        // 32 rows, shared by all 4 waves

    // wave-private stage: group wg (8 KB) -> stg[w][buf], 8 x 1KB gl_lds
    auto stage = [&](int wg, int buf) {
        const _Float16* gsrc = P + (size_t)wg * GRP_F16 + l * 8;
        _Float16* dst = &stg[w][buf][l * 8];
        #pragma unroll
        for (int r = 0; r < 8; ++r) {
            __builtin_amdgcn_global_load_lds(
                (const __attribute__((address_space(1))) void*)(gsrc + r * 512),
                (__attribute__((address_space(3))) void*)(dst + r * 512),
                16, 0, 0);
        }
    };

    // ---- wave-private bias window -> LDS (no cross-wave access, no barrier)
    {
        floatx4 bv = *(const floatx4*)(bias + w * 256 + l * 4);
        *(floatx4*)&bls[w * 256 + l * 4] = bv;
    }

    // ---- A fragments: 2 row-tiles (32 rows), fp32 -> f16, in registers ----
    half8 afrag[2][8];
    #pragma unroll
    for (int h = 0; h < 2; ++h) {
        const float* xr = x + (size_t)(brow0 + h * 16 + l15) * KH;
        #pragma unroll
        for (int ks = 0; ks < 8; ++ks) {
            const int kb = ks * 32 + lq * 8;
            floatx4 lo = *(const floatx4*)(xr + kb);
            floatx4 hi = *(const floatx4*)(xr + kb + 4);
            half8 f;
            f[0] = (_Float16)lo[0]; f[1] = (_Float16)lo[1];
            f[2] = (_Float16)lo[2]; f[3] = (_Float16)lo[3];
            f[4] = (_Float16)hi[0]; f[5] = (_Float16)hi[1];
            f[6] = (_Float16)hi[2]; f[7] = (_Float16)hi[3];
            afrag[h][ks] = f;
        }
    }
    // drain x/bias loads so they never appear in the loop's vmcnt accounting
    asm volatile("s_waitcnt vmcnt(0)" ::: "memory");

    stage(w * NGRP + 0, 0);    // 8 ops
    stage(w * NGRP + 1, 1);    // 8 ops

    float* orow0 = out + (size_t)(brow0 + l15) * NN;
    float* orow1 = orow0 + (size_t)16 * NN;

    // per-iter VMEM ops: 8 stage + 2 stores. steady-state wait leaves
    // [next stage (8) + last 2 iters' stores (4)] in flight = vmcnt(12)
#define DO_ITER(G, WAITN) do {                                                  \
        asm volatile("s_waitcnt vmcnt(" #WAITN ")" ::: "memory");               \
        const _Float16* fb = &stg[w][(G) & 1][l * 8];                           \
        floatx4 a0 = (floatx4)0.0f, a1 = (floatx4)0.0f;                         \
        _Pragma("unroll")                                                       \
        for (int ks = 0; ks < 8; ++ks) {                                        \
            half8 wf = *(const half8*)(fb + ks * 512);                          \
            a0 = __builtin_amdgcn_mfma_f32_16x16x32_f16(wf, afrag[0][ks], a0, 0, 0, 0); \
            a1 = __builtin_amdgcn_mfma_f32_16x16x32_f16(wf, afrag[1][ks], a1, 0, 0, 0); \
        }                                                                       \
        __builtin_amdgcn_sched_barrier(0);                                      \
        if ((G) + 2 < NGRP) stage(w * NGRP + (G) + 2, (G) & 1);                 \
        __builtin_amdgcn_sched_barrier(0);                                      \
        const int nb = (w * NGRP + (G)) * 16 + lq * 4;                          \
        floatx4 bv = *(const floatx4*)&bls[w * 256 + ((G) * 16 + lq * 4)];      \
        floatx4 r0, r1;                                                         \
        _Pragma("unroll")                                                       \
        for (int j = 0; j < 4; ++j) {                                           \
            r0[j] = __builtin_amdgcn_rcpf(1.0f + __expf(-(a0[j] + bv[j])));     \
            r1[j] = __builtin_amdgcn_rcpf(1.0f + __expf(-(a1[j] + bv[j])));     \
        }                                                                       \
        __builtin_nontemporal_store(r0, (floatx4*)(orow0 + nb));                \
        __builtin_nontemporal_store(r1, (floatx4*)(orow1 + nb));                \
    } while (0)

    DO_ITER(0, 8);     // [stg0(8) stg1(8)] -> drain stg0
    DO_ITER(1, 10);    // [stg1(8) stg2(8) st0(2)] -> drain stg1
    DO_ITER(2, 12);    // steady state from here
    DO_ITER(3, 12);
    DO_ITER(4, 12);
    DO_ITER(5, 12);
    DO_ITER(6, 12);
    DO_ITER(7, 12);
    DO_ITER(8, 12);
    DO_ITER(9, 12);
    DO_ITER(10, 12);
    DO_ITER(11, 12);
    DO_ITER(12, 12);
    DO_ITER(13, 12);   // last stage issued here (group 15)
    DO_ITER(14, 12);   // no stage (14+2 >= 16)
    DO_ITER(15, 4);    // [stg15(8) st13(2) st14(2)] -> drain stg15
#undef DO_ITER
}

extern "C" void kernel_launch(void* const* d_in, const int* in_sizes, int n_in,
                              void* d_out, int out_size, void* d_ws, size_t ws_size,
                              hipStream_t stream) {
    const float* x = (const float*)d_in[0];
    const float* W = (const float*)d_in[1];
    const float* b = (const float*)d_in[2];
    float* out = (float*)d_out;
    _Float16* P = (_Float16*)d_ws;            // 512 KB packed f16 W

    pack_w<<<dim3(128), dim3(256), 0, stream>>>(W, P);

    const int Btot = in_sizes[0] / KH;        // 32768
    lfh_main<<<dim3(Btot / BM), dim3(THREADS), 0, stream>>>(x, P, b, out);
}